// Round 1
// baseline (183.869 us; speedup 1.0000x reference)
//
#include <hip/hip_runtime.h>

namespace {

typedef __attribute__((ext_vector_type(2))) float f32x2;
typedef __attribute__((ext_vector_type(4))) float f32x4;

constexpr int Hd = 512, Wd = 512;
constexpr int TH = 32;             // output rows per block (band)
constexpr int R  = 4;              // rows per LDS phase (barrier period)
constexpr int NCH = TH / R;        // 8 chunks
constexpr int RAD = 5, WS = 11;
constexpr int HSTR = 524;          // 5+512+5=522 used, padded (4*524=2096, mult of 8)
constexpr float C1c = 1e-4f;       // (0.01*1.0)^2
constexpr float C2c = 9e-4f;       // (0.03*1.0)^2

__device__ __forceinline__ float rcp_fast(float x) { return __builtin_amdgcn_rcpf(x); }
__device__ __forceinline__ float sgpr_f(float x) {
    return __int_as_float(__builtin_amdgcn_readfirstlane(__float_as_int(x)));
}

// XOR-swizzle on the f32x4-element index. The horizontal read pattern
// (lane stride 4 elements = 64 B = 16 dwords) concentrates 64 lanes onto
// 2 of the 8 four-bank groups -> ~12 extra cycles per ds_read_b128
// (8.26M SQ_LDS_BANK_CONFLICT cycles ~= 21% of kernel). XORing the low-3
// element bits with bits 3..5 spreads each wave's read across all 8 bank
// groups exactly 8 lanes each (dense, bandwidth-floor). The map permutes
// only within aligned-8 blocks: bijective, stays in-bounds (array size
// 2096 is a multiple of 8), keeps 16-B alignment. Writes (contiguous
// lane stride 1 element) remain dense under the same map.
__device__ __forceinline__ int swz(int e) { return e ^ ((e >> 3) & 7); }

// LDS 33.5 KB (4 blocks/CU fit); VGPR capped at 85 by (512,6)
__global__ __launch_bounds__(512, 6) void ssim_map_kernel(
    const float* __restrict__ img1,
    const float* __restrict__ img2,
    const float* __restrict__ kern,
    float* __restrict__ out)
{
    // packed {mS, mD, QS, QD} per column, R rows
    __shared__ __align__(16) f32x4 hb[R * HSTR];   // 33.5 KB

    const int tid  = threadIdx.x;
    const int c    = tid;                       // owned column
    const int row0 = blockIdx.x * TH;
    const long pbase = (long)blockIdx.y * (long)(Hd * Wd);

    // ---- 1D gaussian (uniform -> SGPRs): g[j] = k[5][j]/sum ----
    float g[WS];
    {
        float s = 0.f;
#pragma unroll
        for (int j = 0; j < WS; ++j) s += kern[RAD * WS + j];
        const float inv = 1.0f / s;
#pragma unroll
        for (int j = 0; j < WS; ++j) g[j] = sgpr_f(kern[RAD * WS + j] * inv);
    }

    // ---- ring accumulators, slot(out_row o) = o % 11 ----
    f32x2 aM[WS];   // {conv(S), conv(D)}
    f32x2 aQ[WS];   // {conv(S^2), conv(D^2)}
#pragma unroll
    for (int i = 0; i < WS; ++i) {
        aM[i].x = 0.f; aM[i].y = 0.f;
        aQ[i].x = 0.f; aQ[i].y = 0.f;
    }

    // ---- fill: input idx j=0..9 (rows row0-5+j), taps k<=j ----
#pragma unroll
    for (int j = 0; j < 2 * RAD; ++j) {
        int gr = row0 - RAD + j;                // uniform reflect -> SALU
        gr = (gr < 0) ? -gr : gr;
        gr = (gr >= Hd) ? (2 * Hd - 2 - gr) : gr;
        const long off = pbase + (long)gr * Wd + c;
        const float a = img1[off];
        const float b = img2[off];
        f32x2 sd; sd.x = a + b; sd.y = a - b;
        const f32x2 qq = sd * sd;               // v_pk_mul_f32
#pragma unroll
        for (int k = 0; k < WS; ++k) {
            if (k <= j) {
                const int slot = (j - k) % WS;  // static after unroll
                f32x2 w2; w2.x = g[k]; w2.y = g[k];
                aM[slot] = __builtin_elementwise_fma(w2, sd, aM[slot]);
                aQ[slot] = __builtin_elementwise_fma(w2, qq, aQ[slot]);
            }
        }
    }

    const int hr = tid >> 7;      // horizontal: row in chunk (0..3)
    const int hu = tid & 127;     // horizontal: out cols 4hu..4hu+3

#pragma unroll
    for (int ch = 0; ch < NCH; ++ch) {
        __syncthreads();          // prev chunk's readers done before overwrite

        // ---- vertical: 1 input row -> 1 completed output row ----
#pragma unroll
        for (int i = 0; i < R; ++i) {
            const int o = ch * R + i;           // out row in band
            const int j = o + 2 * RAD;          // input idx
            int gr = row0 - RAD + j;            // reflect (uniform)
            gr = (gr < 0) ? -gr : gr;
            gr = (gr >= Hd) ? (2 * Hd - 2 - gr) : gr;
            const long off = pbase + (long)gr * Wd + c;
            const float a = img1[off];
            const float b = img2[off];
            f32x2 sd; sd.x = a + b; sd.y = a - b;
            const f32x2 qq = sd * sd;
#pragma unroll
            for (int k = 0; k < WS; ++k) {
                const int slot = (j - k) % WS;  // static after unroll
                f32x2 w2; w2.x = g[k]; w2.y = g[k];
                aM[slot] = __builtin_elementwise_fma(w2, sd, aM[slot]);
                aQ[slot] = __builtin_elementwise_fma(w2, qq, aQ[slot]);
            }
            // emit completed row o (slot o%11) -> LDS row i, one b128
            const int es = o % WS;
            f32x4 e;
            e.x = aM[es].x; e.y = aM[es].y;
            e.z = aQ[es].x; e.w = aQ[es].y;
            hb[swz(i * HSTR + RAD + c)] = e;
            if (c >= 1 && c <= RAD) {                       // left reflect halo
                hb[swz(i * HSTR + RAD - c)] = e;
            } else if (c >= Wd - 1 - RAD && c <= Wd - 2) {  // right reflect halo
                hb[swz(i * HSTR + RAD + 1022 - c)] = e;
            }
            aM[es].x = 0.f; aM[es].y = 0.f;     // free slot for row o+11
            aQ[es].x = 0.f; aQ[es].y = 0.f;
        }

        __syncthreads();

        // ---- horizontal + epilogue: 4 cols x 1 row per thread ----
        // streams one f32x4 at a time to keep register pressure low
        f32x2 hm[4], hq[4];
#pragma unroll
        for (int j = 0; j < 4; ++j) {
            hm[j].x = 0.f; hm[j].y = 0.f;
            hq[j].x = 0.f; hq[j].y = 0.f;
        }
        const int e0 = hr * HSTR + 4 * hu;
#pragma unroll
        for (int t = 0; t < 14; ++t) {          // staged idx 4hu+t (col 4hu+t-5)
            const f32x4 ft = hb[swz(e0 + t)];   // ds_read_b128, swizzled
            f32x2 fm; fm.x = ft.x; fm.y = ft.y;
            f32x2 fq; fq.x = ft.z; fq.y = ft.w;
#pragma unroll
            for (int j = 0; j < 4; ++j) {
                const int k = t - j;            // tap index, compile-time
                if (k >= 0 && k < WS) {
                    f32x2 w2; w2.x = g[k]; w2.y = g[k];
                    hm[j] = __builtin_elementwise_fma(w2, fm, hm[j]);
                    hq[j] = __builtin_elementwise_fma(w2, fq, hq[j]);
                }
            }
        }

        float rr[4];
#pragma unroll
        for (int j = 0; j < 4; ++j) {
            const f32x2 m = hm[j];              // {mS, mD}
            const f32x2 q = hq[j];              // {QS, QD}
            const f32x2 msq = m * m;            // {mS^2, mD^2}
            const float t1 = msq.x - msq.y;     // 4*mu1mu2
            const float t2 = msq.x + msq.y;     // 2*(mu1^2+mu2^2)
            const float q1 = q.x - q.y;         // 4*conv(ab)
            const float q2 = q.x + q.y;         // 2*conv(a^2+b^2)
            const float num = fmaf(0.5f, t1, C1c) * fmaf(0.5f, q1 - t1, C2c);
            const float den = fmaf(0.5f, t2, C1c) * fmaf(0.5f, q2 - t2, C2c);
            rr[j] = num * rcp_fast(den);
        }
        f32x4 res; res.x = rr[0]; res.y = rr[1]; res.z = rr[2]; res.w = rr[3];
        f32x4* po = (f32x4*)&out[pbase + (long)(row0 + ch * R + hr) * Wd + 4 * hu];
        *po = res;
    }
}

} // namespace

extern "C" void kernel_launch(void* const* d_in, const int* in_sizes, int n_in,
                              void* d_out, int out_size, void* d_ws, size_t ws_size,
                              hipStream_t stream) {
    const float* img1 = (const float*)d_in[0];
    const float* img2 = (const float*)d_in[1];
    const float* kern = (const float*)d_in[2];
    float* outp = (float*)d_out;
    dim3 grid(Hd / TH, 48);   // 16 bands x 48 planes = 768 blocks = 3/CU
    ssim_map_kernel<<<grid, dim3(512), 0, stream>>>(img1, img2, kern, outp);
}

// Round 2
// 165.078 us; speedup vs baseline: 1.1138x; 1.1138x over previous
//
#include <hip/hip_runtime.h>

namespace {

typedef __attribute__((ext_vector_type(2))) float f32x2;
typedef __attribute__((ext_vector_type(4))) float f32x4;

constexpr int Hd = 512, Wd = 512;
constexpr int TH = 16;             // output rows per block (band). 16 -> 1536 blocks
                                   // = 6/CU scheduled, 4/CU resident (LDS-limited),
                                   // vs TH=32's exact-3/CU with no refill slack
                                   // (round-0 OccupancyPercent was only 51%).
constexpr int R  = 4;              // rows per LDS phase (barrier period)
constexpr int NCH = TH / R;        // 4 chunks
constexpr int RAD = 5, WS = 11;
constexpr int HSTR = 524;          // 5+512+5=522 used, padded
constexpr float C1c = 1e-4f;       // (0.01*1.0)^2
constexpr float C2c = 9e-4f;       // (0.03*1.0)^2

__device__ __forceinline__ float rcp_fast(float x) { return __builtin_amdgcn_rcpf(x); }
__device__ __forceinline__ float sgpr_f(float x) {
    return __int_as_float(__builtin_amdgcn_readfirstlane(__float_as_int(x)));
}

// NOTE (round-1 post-mortem): LDS XOR-swizzle of this buffer halved
// SQ_LDS_BANK_CONFLICT (8.26M->4.33M) but REGRESSED time 64.8->85us:
// per-use swz() recompute serialized every ds_read behind its address
// math and killed the base+offset-immediate addressing. Conflicts here
// overlap with other waves' VALU and are not on the critical path.
// Keep the linear layout.

// LDS 33.5 KB (4 blocks/CU fit); VGPR 40 < 64 so 8 waves/EU tier is reachable
__global__ __launch_bounds__(512, 8) void ssim_map_kernel(
    const float* __restrict__ img1,
    const float* __restrict__ img2,
    const float* __restrict__ kern,
    float* __restrict__ out)
{
    // packed {mS, mD, QS, QD} per column, R rows
    __shared__ __align__(16) f32x4 hb[R * HSTR];   // 33.5 KB

    const int tid  = threadIdx.x;
    const int c    = tid;                       // owned column
    const int row0 = blockIdx.x * TH;
    const long pbase = (long)blockIdx.y * (long)(Hd * Wd);

    // ---- 1D gaussian (uniform -> SGPRs): g[j] = k[5][j]/sum ----
    float g[WS];
    {
        float s = 0.f;
#pragma unroll
        for (int j = 0; j < WS; ++j) s += kern[RAD * WS + j];
        const float inv = 1.0f / s;
#pragma unroll
        for (int j = 0; j < WS; ++j) g[j] = sgpr_f(kern[RAD * WS + j] * inv);
    }

    // ---- ring accumulators, slot(out_row o) = o % 11 ----
    f32x2 aM[WS];   // {conv(S), conv(D)}
    f32x2 aQ[WS];   // {conv(S^2), conv(D^2)}
#pragma unroll
    for (int i = 0; i < WS; ++i) {
        aM[i].x = 0.f; aM[i].y = 0.f;
        aQ[i].x = 0.f; aQ[i].y = 0.f;
    }

    // ---- fill: input idx j=0..9 (rows row0-5+j), taps k<=j ----
#pragma unroll
    for (int j = 0; j < 2 * RAD; ++j) {
        int gr = row0 - RAD + j;                // uniform reflect -> SALU
        gr = (gr < 0) ? -gr : gr;
        gr = (gr >= Hd) ? (2 * Hd - 2 - gr) : gr;
        const long off = pbase + (long)gr * Wd + c;
        const float a = img1[off];
        const float b = img2[off];
        f32x2 sd; sd.x = a + b; sd.y = a - b;
        const f32x2 qq = sd * sd;               // v_pk_mul_f32
#pragma unroll
        for (int k = 0; k < WS; ++k) {
            if (k <= j) {
                const int slot = (j - k) % WS;  // static after unroll
                f32x2 w2; w2.x = g[k]; w2.y = g[k];
                aM[slot] = __builtin_elementwise_fma(w2, sd, aM[slot]);
                aQ[slot] = __builtin_elementwise_fma(w2, qq, aQ[slot]);
            }
        }
    }

    const int hr = tid >> 7;      // horizontal: row in chunk (0..3)
    const int hu = tid & 127;     // horizontal: out cols 4hu..4hu+3

#pragma unroll
    for (int ch = 0; ch < NCH; ++ch) {
        __syncthreads();          // prev chunk's readers done before overwrite

        // ---- vertical: 1 input row -> 1 completed output row ----
#pragma unroll
        for (int i = 0; i < R; ++i) {
            const int o = ch * R + i;           // out row in band
            const int j = o + 2 * RAD;          // input idx
            int gr = row0 - RAD + j;            // reflect (uniform)
            gr = (gr < 0) ? -gr : gr;
            gr = (gr >= Hd) ? (2 * Hd - 2 - gr) : gr;
            const long off = pbase + (long)gr * Wd + c;
            const float a = img1[off];
            const float b = img2[off];
            f32x2 sd; sd.x = a + b; sd.y = a - b;
            const f32x2 qq = sd * sd;
#pragma unroll
            for (int k = 0; k < WS; ++k) {
                const int slot = (j - k) % WS;  // static after unroll
                f32x2 w2; w2.x = g[k]; w2.y = g[k];
                aM[slot] = __builtin_elementwise_fma(w2, sd, aM[slot]);
                aQ[slot] = __builtin_elementwise_fma(w2, qq, aQ[slot]);
            }
            // emit completed row o (slot o%11) -> LDS row i, one b128
            const int es = o % WS;
            f32x4 e;
            e.x = aM[es].x; e.y = aM[es].y;
            e.z = aQ[es].x; e.w = aQ[es].y;
            hb[i * HSTR + RAD + c] = e;
            if (c >= 1 && c <= RAD) {                       // left reflect halo
                hb[i * HSTR + RAD - c] = e;
            } else if (c >= Wd - 1 - RAD && c <= Wd - 2) {  // right reflect halo
                hb[i * HSTR + RAD + 1022 - c] = e;
            }
            aM[es].x = 0.f; aM[es].y = 0.f;     // free slot for row o+11
            aQ[es].x = 0.f; aQ[es].y = 0.f;
        }

        __syncthreads();

        // ---- horizontal + epilogue: 4 cols x 1 row per thread ----
        // streams one f32x4 at a time to keep register pressure low
        f32x2 hm[4], hq[4];
#pragma unroll
        for (int j = 0; j < 4; ++j) {
            hm[j].x = 0.f; hm[j].y = 0.f;
            hq[j].x = 0.f; hq[j].y = 0.f;
        }
        const f32x4* base = &hb[hr * HSTR + 4 * hu];
#pragma unroll
        for (int t = 0; t < 14; ++t) {          // staged idx 4hu+t (col 4hu+t-5)
            const f32x4 ft = base[t];           // ds_read_b128
            f32x2 fm; fm.x = ft.x; fm.y = ft.y;
            f32x2 fq; fq.x = ft.z; fq.y = ft.w;
#pragma unroll
            for (int j = 0; j < 4; ++j) {
                const int k = t - j;            // tap index, compile-time
                if (k >= 0 && k < WS) {
                    f32x2 w2; w2.x = g[k]; w2.y = g[k];
                    hm[j] = __builtin_elementwise_fma(w2, fm, hm[j]);
                    hq[j] = __builtin_elementwise_fma(w2, fq, hq[j]);
                }
            }
        }

        float rr[4];
#pragma unroll
        for (int j = 0; j < 4; ++j) {
            const f32x2 m = hm[j];              // {mS, mD}
            const f32x2 q = hq[j];              // {QS, QD}
            const f32x2 msq = m * m;            // {mS^2, mD^2}
            const float t1 = msq.x - msq.y;     // 4*mu1mu2
            const float t2 = msq.x + msq.y;     // 2*(mu1^2+mu2^2)
            const float q1 = q.x - q.y;         // 4*conv(ab)
            const float q2 = q.x + q.y;         // 2*conv(a^2+b^2)
            const float num = fmaf(0.5f, t1, C1c) * fmaf(0.5f, q1 - t1, C2c);
            const float den = fmaf(0.5f, t2, C1c) * fmaf(0.5f, q2 - t2, C2c);
            rr[j] = num * rcp_fast(den);
        }
        f32x4 res; res.x = rr[0]; res.y = rr[1]; res.z = rr[2]; res.w = rr[3];
        f32x4* po = (f32x4*)&out[pbase + (long)(row0 + ch * R + hr) * Wd + 4 * hu];
        *po = res;
    }
}

} // namespace

extern "C" void kernel_launch(void* const* d_in, const int* in_sizes, int n_in,
                              void* d_out, int out_size, void* d_ws, size_t ws_size,
                              hipStream_t stream) {
    const float* img1 = (const float*)d_in[0];
    const float* img2 = (const float*)d_in[1];
    const float* kern = (const float*)d_in[2];
    float* outp = (float*)d_out;
    dim3 grid(Hd / TH, 48);   // 32 bands x 48 planes = 1536 blocks = 6/CU scheduled
    ssim_map_kernel<<<grid, dim3(512), 0, stream>>>(img1, img2, kern, outp);
}

// Round 3
// 153.574 us; speedup vs baseline: 1.1973x; 1.0749x over previous
//
#include <hip/hip_runtime.h>

namespace {

typedef __attribute__((ext_vector_type(2))) float f32x2;
typedef __attribute__((ext_vector_type(4))) float f32x4;

constexpr int Hd = 512, Wd = 512;
constexpr int TH = 32;             // output rows per block. TH=16 (round 2) raised
                                   // occupancy 51->60% but regressed 64.8->71.2us:
                                   // fill overhead (+18% work) outweighed it. Keep 32.
constexpr int R  = 4;              // rows per LDS phase (barrier period)
constexpr int NCH = TH / R;        // 8 chunks
constexpr int RAD = 5, WS = 11;
// Transposed staging layout (round-3): staged element e (column e-5) lives at
// slot s(e) = (e&3)*SPAN + (e>>2). Round-0 linear layout had read lane-stride
// 64B -> all 64 lanes on 2 of 8 bank groups -> +12 cyc/ds_read_b128
// (SQ_LDS_BANK_CONFLICT = 8.26M ~= 21% of kernel), and the horizontal phase is
// the LDS-latency-critical section. With the transpose:
//   reads:  slot(4hu+t) = (t&3)*SPAN + hu + (t>>2) -> ONE base (lane stride
//           16B, dense 1024B/wave) + 14 compile-time immediates. Conflict-free.
//   writes: slot(c+5) precomputed once; wave writes = 4 dense 256B segments.
// Zero per-access VALU added (round-1's swizzle failure mode avoided).
constexpr int SPAN = 131;          // ceil(522/4); row stride = 4*SPAN = 524 elems
constexpr int RSTR = 4 * SPAN;     // f32x4 elements per staged row
constexpr float C1c = 1e-4f;       // (0.01*1.0)^2
constexpr float C2c = 9e-4f;       // (0.03*1.0)^2

__device__ __forceinline__ float rcp_fast(float x) { return __builtin_amdgcn_rcpf(x); }
__device__ __forceinline__ float sgpr_f(float x) {
    return __int_as_float(__builtin_amdgcn_readfirstlane(__float_as_int(x)));
}
__device__ __forceinline__ constexpr int sw(int e) { return (e & 3) * SPAN + (e >> 2); }

// LDS 33.5 KB (4 blocks/CU fit); VGPR capped at 85 by (512,6)
__global__ __launch_bounds__(512, 6) void ssim_map_kernel(
    const float* __restrict__ img1,
    const float* __restrict__ img2,
    const float* __restrict__ kern,
    float* __restrict__ out)
{
    // packed {mS, mD, QS, QD} per column, R rows, transposed slot order
    __shared__ __align__(16) f32x4 hb[R * RSTR];   // 33.5 KB

    const int tid  = threadIdx.x;
    const int c    = tid;                       // owned column
    const int row0 = blockIdx.x * TH;
    const long pbase = (long)blockIdx.y * (long)(Hd * Wd);

    // ---- 1D gaussian (uniform -> SGPRs): g[j] = k[5][j]/sum ----
    float g[WS];
    {
        float s = 0.f;
#pragma unroll
        for (int j = 0; j < WS; ++j) s += kern[RAD * WS + j];
        const float inv = 1.0f / s;
#pragma unroll
        for (int j = 0; j < WS; ++j) g[j] = sgpr_f(kern[RAD * WS + j] * inv);
    }

    // ---- precomputed transposed write slots (loop-invariant) ----
    const int wmain = sw(c + RAD);              // staged element c+5
    int whalo = -1;
    if (c >= 1 && c <= RAD) whalo = sw(RAD - c);                       // left reflect
    else if (c >= Wd - 1 - RAD && c <= Wd - 2) whalo = sw(RAD + 1022 - c); // right

    // ---- ring accumulators, slot(out_row o) = o % 11 ----
    f32x2 aM[WS];   // {conv(S), conv(D)}
    f32x2 aQ[WS];   // {conv(S^2), conv(D^2)}
#pragma unroll
    for (int i = 0; i < WS; ++i) {
        aM[i].x = 0.f; aM[i].y = 0.f;
        aQ[i].x = 0.f; aQ[i].y = 0.f;
    }

    // ---- fill: input idx j=0..9 (rows row0-5+j), taps k<=j ----
#pragma unroll
    for (int j = 0; j < 2 * RAD; ++j) {
        int gr = row0 - RAD + j;                // uniform reflect -> SALU
        gr = (gr < 0) ? -gr : gr;
        gr = (gr >= Hd) ? (2 * Hd - 2 - gr) : gr;
        const long off = pbase + (long)gr * Wd + c;
        const float a = img1[off];
        const float b = img2[off];
        f32x2 sd; sd.x = a + b; sd.y = a - b;
        const f32x2 qq = sd * sd;               // v_pk_mul_f32
#pragma unroll
        for (int k = 0; k < WS; ++k) {
            if (k <= j) {
                const int slot = (j - k) % WS;  // static after unroll
                f32x2 w2; w2.x = g[k]; w2.y = g[k];
                aM[slot] = __builtin_elementwise_fma(w2, sd, aM[slot]);
                aQ[slot] = __builtin_elementwise_fma(w2, qq, aQ[slot]);
            }
        }
    }

    const int hr = tid >> 7;      // horizontal: row in chunk (0..3)
    const int hu = tid & 127;     // horizontal: out cols 4hu..4hu+3

#pragma unroll
    for (int ch = 0; ch < NCH; ++ch) {
        __syncthreads();          // prev chunk's readers done before overwrite

        // ---- vertical: 1 input row -> 1 completed output row ----
#pragma unroll
        for (int i = 0; i < R; ++i) {
            const int o = ch * R + i;           // out row in band
            const int j = o + 2 * RAD;          // input idx
            int gr = row0 - RAD + j;            // reflect (uniform)
            gr = (gr < 0) ? -gr : gr;
            gr = (gr >= Hd) ? (2 * Hd - 2 - gr) : gr;
            const long off = pbase + (long)gr * Wd + c;
            const float a = img1[off];
            const float b = img2[off];
            f32x2 sd; sd.x = a + b; sd.y = a - b;
            const f32x2 qq = sd * sd;
#pragma unroll
            for (int k = 0; k < WS; ++k) {
                const int slot = (j - k) % WS;  // static after unroll
                f32x2 w2; w2.x = g[k]; w2.y = g[k];
                aM[slot] = __builtin_elementwise_fma(w2, sd, aM[slot]);
                aQ[slot] = __builtin_elementwise_fma(w2, qq, aQ[slot]);
            }
            // emit completed row o (slot o%11) -> LDS row i, transposed slot
            const int es = o % WS;
            f32x4 e;
            e.x = aM[es].x; e.y = aM[es].y;
            e.z = aQ[es].x; e.w = aQ[es].y;
            hb[i * RSTR + wmain] = e;
            if (whalo >= 0) hb[i * RSTR + whalo] = e;
            aM[es].x = 0.f; aM[es].y = 0.f;     // free slot for row o+11
            aQ[es].x = 0.f; aQ[es].y = 0.f;
        }

        __syncthreads();

        // ---- horizontal + epilogue: 4 cols x 1 row per thread ----
        f32x2 hm[4], hq[4];
#pragma unroll
        for (int j = 0; j < 4; ++j) {
            hm[j].x = 0.f; hm[j].y = 0.f;
            hq[j].x = 0.f; hq[j].y = 0.f;
        }
        // base lane-stride = 1 element (16B): dense wave reads, all offsets imm
        const f32x4* base = &hb[hr * RSTR + hu];
#pragma unroll
        for (int t = 0; t < 14; ++t) {          // staged elem 4hu+t (col 4hu+t-5)
            const f32x4 ft = base[(t & 3) * SPAN + (t >> 2)];   // ds_read_b128
            f32x2 fm; fm.x = ft.x; fm.y = ft.y;
            f32x2 fq; fq.x = ft.z; fq.y = ft.w;
#pragma unroll
            for (int j = 0; j < 4; ++j) {
                const int k = t - j;            // tap index, compile-time
                if (k >= 0 && k < WS) {
                    f32x2 w2; w2.x = g[k]; w2.y = g[k];
                    hm[j] = __builtin_elementwise_fma(w2, fm, hm[j]);
                    hq[j] = __builtin_elementwise_fma(w2, fq, hq[j]);
                }
            }
        }

        float rr[4];
#pragma unroll
        for (int j = 0; j < 4; ++j) {
            const f32x2 m = hm[j];              // {mS, mD}
            const f32x2 q = hq[j];              // {QS, QD}
            const f32x2 msq = m * m;            // {mS^2, mD^2}
            const float t1 = msq.x - msq.y;     // 4*mu1mu2
            const float t2 = msq.x + msq.y;     // 2*(mu1^2+mu2^2)
            const float q1 = q.x - q.y;         // 4*conv(ab)
            const float q2 = q.x + q.y;         // 2*conv(a^2+b^2)
            const float num = fmaf(0.5f, t1, C1c) * fmaf(0.5f, q1 - t1, C2c);
            const float den = fmaf(0.5f, t2, C1c) * fmaf(0.5f, q2 - t2, C2c);
            rr[j] = num * rcp_fast(den);
        }
        f32x4 res; res.x = rr[0]; res.y = rr[1]; res.z = rr[2]; res.w = rr[3];
        f32x4* po = (f32x4*)&out[pbase + (long)(row0 + ch * R + hr) * Wd + 4 * hu];
        *po = res;
    }
}

} // namespace

extern "C" void kernel_launch(void* const* d_in, const int* in_sizes, int n_in,
                              void* d_out, int out_size, void* d_ws, size_t ws_size,
                              hipStream_t stream) {
    const float* img1 = (const float*)d_in[0];
    const float* img2 = (const float*)d_in[1];
    const float* kern = (const float*)d_in[2];
    float* outp = (float*)d_out;
    dim3 grid(Hd / TH, 48);   // 16 bands x 48 planes = 768 blocks = 3/CU
    ssim_map_kernel<<<grid, dim3(512), 0, stream>>>(img1, img2, kern, outp);
}